// Round 5
// baseline (7942.132 us; speedup 1.0000x reference)
//
#include <hip/hip_runtime.h>
#include <hip/hip_bf16.h>

// ---- problem constants ----
#define BB_ 32      // batch
#define PP_ 196     // pixels
#define DD_ 2048    // encoder dim
#define HH_ 512     // hidden
#define VV_ 30000   // vocab
#define TT_ 19      // timesteps
#define KX_ 2560    // H + D
#define KG_ 3072    // H + D + H
#define NBLK_ 240   // persistent grid (< 256 CUs -> always co-resident)
#define NTV_ 1875   // out-GEMM n-tiles (30000/16)
#define NTH_ 160    // hmats n-tiles (2560/16)

typedef __attribute__((ext_vector_type(8))) short bf16x8;   // 8 bf16 (4 VGPRs)
typedef __attribute__((ext_vector_type(4))) float f32x4;

__device__ __forceinline__ unsigned short bf16b(float x) {
    __hip_bfloat16 h = __float2bfloat16(x);
    unsigned short u; __builtin_memcpy(&u, &h, 2); return u;
}
__device__ __forceinline__ float b2f(unsigned short u) {
    return __uint_as_float((unsigned int)u << 16);
}
__device__ __forceinline__ float sigf(float x) { return 1.f / (1.f + __expf(-x)); }
__device__ __forceinline__ float ftanh(float x) {
    return 1.f - 2.f / (__expf(2.f * x) + 1.f);
}
__device__ __forceinline__ f32x4 mfma16(bf16x8 a, bf16x8 b, f32x4 c) {
    return __builtin_amdgcn_mfma_f32_16x16x32_bf16(a, b, c, 0, 0, 0);
}

// device-scope grid barrier: bar[0]=arrivals, bar[1]=generation (memset to 0 each call)
__device__ __forceinline__ void gbar(unsigned* bar) {
    __syncthreads();
    if (threadIdx.x == 0) {
        __threadfence();   // publish this block's writes device-wide (cross-XCD)
        unsigned gen = __hip_atomic_load(&bar[1], __ATOMIC_RELAXED, __HIP_MEMORY_SCOPE_AGENT);
        unsigned arr = __hip_atomic_fetch_add(&bar[0], 1u, __ATOMIC_ACQ_REL, __HIP_MEMORY_SCOPE_AGENT);
        if (arr == NBLK_ - 1u) {
            __hip_atomic_store(&bar[0], 0u, __ATOMIC_RELAXED, __HIP_MEMORY_SCOPE_AGENT);
            __hip_atomic_fetch_add(&bar[1], 1u, __ATOMIC_RELEASE, __HIP_MEMORY_SCOPE_AGENT);
        } else {
            while (__hip_atomic_load(&bar[1], __ATOMIC_ACQUIRE, __HIP_MEMORY_SCOPE_AGENT) == gen)
                __builtin_amdgcn_s_sleep(1);
        }
        __threadfence();   // acquire: invalidate stale cached lines
    }
    __syncthreads();
}

// ---------------- fused conversion kernel (one launch) ----------------

__device__ __forceinline__ void d_cvt8(int bid, int tid,
        const float* __restrict__ src, unsigned short* __restrict__ dst) {
    size_t i0 = ((size_t)bid * 256 + tid) * 8;
    float4 a = *(const float4*)&src[i0];
    float4 b = *(const float4*)&src[i0 + 4];
    bf16x8 v;
    v[0]=bf16b(a.x); v[1]=bf16b(a.y); v[2]=bf16b(a.z); v[3]=bf16b(a.w);
    v[4]=bf16b(b.x); v[5]=bf16b(b.y); v[6]=bf16b(b.z); v[7]=bf16b(b.w);
    *(bf16x8*)&dst[i0] = v;
}

// Pre-fragment row-major f32 W[K][N] into per-lane MFMA B-fragment order.
// Fragment f = ((nt*(K/32)+ks)*64+lane); lane=16g+r holds B[ks*32+8g+i][nt*16+r].
__device__ __forceinline__ void d_nsplit(int bid, int tid,
        const float* __restrict__ A, int NA, const float* __restrict__ Bp, int NB,
        int K, unsigned short* __restrict__ dst) {
    int gid = bid * 256 + tid;
    int lane = gid & 63, rest = gid >> 6;
    int KS = K >> 5;
    int ks = rest % KS, nt = rest / KS;
    int g = lane >> 4, r = lane & 15;
    int k0 = ks * 32 + g * 8;
    int n = nt * 16 + r;
    const float* src; int stride, col;
    if (n < NA) { src = A; stride = NA; col = n; }
    else        { src = Bp; stride = NB; col = n - NA; }
    bf16x8 v;
#pragma unroll
    for (int i = 0; i < 8; i++)
        v[i] = bf16b(src[(size_t)(k0 + i) * stride + col]);
    *(bf16x8*)&dst[(size_t)gid * 8] = v;
}

__device__ __forceinline__ void d_ksplit(int bid, int tid,
        const float* __restrict__ A, int KA, const float* __restrict__ Bp,
        int K, int N, unsigned short* __restrict__ dst) {
    int gid = bid * 256 + tid;
    int lane = gid & 63, rest = gid >> 6;
    int KS = K >> 5;
    int ks = rest % KS, nt = rest / KS;
    int g = lane >> 4, r = lane & 15;
    int k0 = ks * 32 + g * 8;
    int n = nt * 16 + r;
    bf16x8 v;
#pragma unroll
    for (int i = 0; i < 8; i++) {
        int k = k0 + i;
        const float* src = (k < KA) ? &A[(size_t)k * N] : &Bp[(size_t)(k - KA) * N];
        v[i] = bf16b(src[n]);
    }
    *(bf16x8*)&dst[(size_t)gid * 8] = v;
}

// block ranges: img 6272 | wout 7500 | wai 512 | whf 640 | wgf 3072 | wif 1024
__global__ __launch_bounds__(256) void k_cvt_all(
        const float* __restrict__ img, unsigned short* __restrict__ imgb,
        const float* __restrict__ Wout, unsigned short* __restrict__ wof,
        const float* __restrict__ Wai, unsigned short* __restrict__ waf,
        const float* __restrict__ Wah, const float* __restrict__ Wfb,
        unsigned short* __restrict__ whf,
        const float* __restrict__ Wih, const float* __restrict__ Whh,
        unsigned short* __restrict__ wgf,
        const float* __restrict__ Winh, const float* __restrict__ Winc,
        unsigned short* __restrict__ wif) {
    int b = blockIdx.x, t = threadIdx.x;
    if (b < 6272)       d_cvt8(b, t, img, imgb);
    else if (b < 13772) d_nsplit(b - 6272, t, Wout, VV_, Wout, 0, HH_, wof);
    else if (b < 14284) d_nsplit(b - 13772, t, Wai, HH_, Wai, 0, DD_, waf);
    else if (b < 14924) d_nsplit(b - 14284, t, Wah, HH_, Wfb, DD_, HH_, whf);
    else if (b < 17996) d_ksplit(b - 14924, t, Wih, KX_, Whh, KG_, 2048, wgf);
    else                d_nsplit(b - 17996, t, Winh, HH_, Winc, HH_, DD_, wif);
}

// ---------------- precompute ----------------

__global__ __launch_bounds__(256) void k_meanpool(const float* __restrict__ img,
                                                  unsigned short* __restrict__ avgb) {
    int b = blockIdx.x, tid = threadIdx.x;
    int d0 = tid * 8;
    const float* p = img + (size_t)b * PP_ * DD_ + d0;
    float s[8] = {};
    for (int i = 0; i < PP_; i++) {
        float4 a = *(const float4*)&p[(size_t)i * DD_];
        float4 c = *(const float4*)&p[(size_t)i * DD_ + 4];
        s[0]+=a.x; s[1]+=a.y; s[2]+=a.z; s[3]+=a.w;
        s[4]+=c.x; s[5]+=c.y; s[6]+=c.z; s[7]+=c.w;
    }
    bf16x8 v;
#pragma unroll
    for (int i = 0; i < 8; i++) v[i] = bf16b(s[i] * (1.0f / PP_));
    *(bf16x8*)&avgb[b * DD_ + d0] = v;
}

// h0/c0 = tanh(avg @ [Winh|Winc] + b) via MFMA; M=32,K=2048,N=1024
__global__ __launch_bounds__(256) void k_init_mfma(const unsigned short* __restrict__ avgb,
        const unsigned short* __restrict__ wif, const float* __restrict__ binh,
        const float* __restrict__ binc, float* __restrict__ c,
        unsigned short* __restrict__ hb) {
    int wid = blockIdx.x * 4 + (threadIdx.x >> 6);   // 0..63 n-tiles
    int lane = threadIdx.x & 63;
    int g = lane >> 4, r = lane & 15;
    f32x4 acc[2] = {};
    const unsigned short* a_base = avgb + (size_t)r * DD_ + g * 8;
#pragma unroll 4
    for (int ks = 0; ks < DD_ / 32; ks++) {
        bf16x8 a0 = *(const bf16x8*)(a_base + ks * 32);
        bf16x8 a1 = *(const bf16x8*)(a_base + 16 * DD_ + ks * 32);
        bf16x8 bf = *(const bf16x8*)(wif + ((size_t)(wid * 64 + ks) * 64 + lane) * 8);
        acc[0] = mfma16(a0, bf, acc[0]);
        acc[1] = mfma16(a1, bf, acc[1]);
    }
    int n = wid * 16 + r;
#pragma unroll
    for (int a = 0; a < 2; a++)
#pragma unroll
        for (int j = 0; j < 4; j++) {
            int m = 16 * a + 4 * g + j;
            float v = ftanh(acc[a][j] + ((n < HH_) ? binh[n] : binc[n - HH_]));
            if (n < HH_) hb[m * HH_ + n] = bf16b(v);
            else c[m * HH_ + (n - HH_)] = v;
        }
}

// att_img(bf16) = img @ W_att_img + b : [6272,2048]x[2048,512]; wave tile 64x64
__global__ __launch_bounds__(256) void k_attimg_mfma(const unsigned short* __restrict__ imgb,
        const unsigned short* __restrict__ waf, const float* __restrict__ bias,
        unsigned short* __restrict__ attb) {
    int wid = blockIdx.x * 4 + (threadIdx.x >> 6);   // 0..783
    int lane = threadIdx.x & 63;
    int g = lane >> 4, r = lane & 15;
    int mt = wid >> 3, ntb = wid & 7;
    int m0 = mt * 64, nt0 = ntb * 4;
    f32x4 acc[4][4] = {};
    const unsigned short* a_base = imgb + (size_t)(m0 + r) * DD_ + g * 8;
    for (int ks = 0; ks < DD_ / 32; ks++) {
        bf16x8 a[4], b[4];
#pragma unroll
        for (int mi = 0; mi < 4; mi++)
            a[mi] = *(const bf16x8*)(a_base + (size_t)(16 * mi) * DD_ + ks * 32);
#pragma unroll
        for (int ni = 0; ni < 4; ni++)
            b[ni] = *(const bf16x8*)(waf + (((size_t)(nt0 + ni) * 64 + ks) * 64 + lane) * 8);
#pragma unroll
        for (int mi = 0; mi < 4; mi++)
#pragma unroll
            for (int ni = 0; ni < 4; ni++)
                acc[mi][ni] = mfma16(a[mi], b[ni], acc[mi][ni]);
    }
#pragma unroll
    for (int mi = 0; mi < 4; mi++)
#pragma unroll
        for (int ni = 0; ni < 4; ni++) {
            int n = (nt0 + ni) * 16 + r;
            float bn = bias[n];
#pragma unroll
            for (int j = 0; j < 4; j++) {
                int m = m0 + 16 * mi + 4 * g + j;
                attb[(size_t)m * HH_ + n] = bf16b(acc[mi][ni][j] + bn);
            }
        }
}

// [hWatt | gate] = h @ [Wah | Wfb] (+bias, sigmoid on gate); wid = n-tile
__device__ __forceinline__ void hmats_body(int wid, int lane,
        const unsigned short* __restrict__ hb, const unsigned short* __restrict__ whf,
        const float* __restrict__ bah, const float* __restrict__ bfb,
        float* __restrict__ hWatt, float* __restrict__ gate) {
    int g = lane >> 4, r = lane & 15;
    f32x4 acc[2] = {};
    const unsigned short* a_base = hb + (size_t)r * HH_ + g * 8;
#pragma unroll
    for (int ks = 0; ks < HH_ / 32; ks++) {
        bf16x8 a0 = *(const bf16x8*)(a_base + ks * 32);
        bf16x8 a1 = *(const bf16x8*)(a_base + 16 * HH_ + ks * 32);
        bf16x8 bf = *(const bf16x8*)(whf + ((size_t)(wid * 16 + ks) * 64 + lane) * 8);
        acc[0] = mfma16(a0, bf, acc[0]);
        acc[1] = mfma16(a1, bf, acc[1]);
    }
    int n = wid * 16 + r;
#pragma unroll
    for (int a = 0; a < 2; a++)
#pragma unroll
        for (int j = 0; j < 4; j++) {
            int m = 16 * a + 4 * g + j;
            float v = acc[a][j];
            if (n < HH_) hWatt[m * HH_ + n] = v + bah[n];
            else gate[m * DD_ + (n - HH_)] = sigf(v + bfb[n - HH_]);
        }
}

// ---------------- persistent step-loop kernel ----------------

__global__ __launch_bounds__(1024) void k_persist(
        const unsigned short* __restrict__ attb, const unsigned short* __restrict__ imgb,
        const unsigned short* __restrict__ wgf, const unsigned short* __restrict__ wof,
        const unsigned short* __restrict__ whf,
        const float* __restrict__ bih, const float* __restrict__ bhh,
        const float* __restrict__ bout, const float* __restrict__ bah,
        const float* __restrict__ bfb, const float* __restrict__ v_att,
        const float* __restrict__ b_v, const float* __restrict__ Emb,
        const int* __restrict__ caps,
        float* __restrict__ c, unsigned short* __restrict__ hb,
        unsigned short* __restrict__ xhb, float* __restrict__ hWatt,
        float* __restrict__ gate, float* __restrict__ preds,
        float* __restrict__ alphas, unsigned* __restrict__ bar) {
    __shared__ float s_part[16][BB_][16];   // 32 KB (PH2)
    __shared__ float s_gsum[4][BB_][16];    //  8 KB (PH2)
    __shared__ float s_e[PP_];
    __shared__ float s_sa[PP_];
    __shared__ float s_red[256];
    const int tid = threadIdx.x;
    const int wv = tid >> 6, lane = tid & 63;
    const int g = lane >> 4, r = lane & 15;
    const int blk = blockIdx.x;

    // PH0: initial hmats from h0
    {
        int wid = blk * 16 + wv;
        if (wid < NTH_) hmats_body(wid, lane, hb, whf, bah, bfb, hWatt, gate);
    }
    gbar(bar);

    for (int t = 0; t < TT_; t++) {
        // ---- PH1: attention, per-b (blocks 0..127; 4 blocks per b) ----
        if (blk < 128) {
            const int b = blk >> 2, quarter = blk & 3;
            {   // energy (replicated across the 4 quarter-blocks)
                const float* hw = hWatt + (size_t)b * HH_ + lane * 8;
                float4 h0 = *(const float4*)&hw[0];
                float4 h1 = *(const float4*)&hw[4];
                const float* vp = v_att + lane * 8;
                float4 v0 = *(const float4*)&vp[0];
                float4 v1 = *(const float4*)&vp[4];
                float hw8[8] = {h0.x,h0.y,h0.z,h0.w,h1.x,h1.y,h1.z,h1.w};
                float vv8[8] = {v0.x,v0.y,v0.z,v0.w,v1.x,v1.y,v1.z,v1.w};
                float bv0 = b_v[0];
                const unsigned short* ab = attb + (size_t)b * PP_ * HH_ + lane * 8;
                for (int p = wv; p < PP_; p += 16) {
                    bf16x8 av = *(const bf16x8*)(ab + (size_t)p * HH_);
                    float acc = 0.f;
#pragma unroll
                    for (int j = 0; j < 8; j++)
                        acc += vv8[j] * ftanh(b2f((unsigned short)av[j]) + hw8[j]);
#pragma unroll
                    for (int off = 32; off > 0; off >>= 1) acc += __shfl_down(acc, off);
                    if (lane == 0) s_e[p] = acc + bv0;
                }
            }
            __syncthreads();
            float ev = (tid < PP_) ? s_e[tid] : -1e30f;
            if (tid < 256) s_red[tid] = ev;
            __syncthreads();
            for (int s = 128; s > 0; s >>= 1) {
                if (tid < s) s_red[tid] = fmaxf(s_red[tid], s_red[tid + s]);
                __syncthreads();
            }
            float mx = s_red[0];
            __syncthreads();
            float pv = (tid < PP_) ? __expf(ev - mx) : 0.f;
            if (tid < 256) s_red[tid] = pv;
            __syncthreads();
            for (int s = 128; s > 0; s >>= 1) {
                if (tid < s) s_red[tid] += s_red[tid + s];
                __syncthreads();
            }
            float inv = 1.f / s_red[0];
            if (tid < PP_) s_sa[tid] = pv * inv;
            __syncthreads();
            if (tid < 256) {
                // context for this 512-wide quarter (2 cols/thread)
                int d0 = quarter * 512 + tid * 2;
                const unsigned short* ib = imgb + (size_t)b * PP_ * DD_ + d0;
                float a0 = 0.f, a1 = 0.f;
#pragma unroll 4
                for (int p = 0; p < PP_; p++) {
                    unsigned int v = *(const unsigned int*)&ib[(size_t)p * DD_];
                    float s = s_sa[p];
                    a0 += s * __uint_as_float(v << 16);
                    a1 += s * __uint_as_float(v & 0xffff0000u);
                }
                float2 gv = *(const float2*)&gate[b * DD_ + d0];
                unsigned int pk = (unsigned int)bf16b(gv.x * a0)
                                | ((unsigned int)bf16b(gv.y * a1) << 16);
                *(unsigned int*)&xhb[b * KG_ + HH_ + d0] = pk;
            } else if (quarter == 0 && tid >= 512) {
                if (tid < 640) {              // emb -> xh[0:512)
                    int i = tid - 512;
                    int tok = caps[b * 20 + t];
                    float4 evec = *(const float4*)&Emb[(size_t)tok * HH_ + i * 4];
                    unsigned int e01 = (unsigned int)bf16b(evec.x) | ((unsigned int)bf16b(evec.y) << 16);
                    unsigned int e23 = (unsigned int)bf16b(evec.z) | ((unsigned int)bf16b(evec.w) << 16);
                    *(uint2*)&xhb[b * KG_ + i * 4] = make_uint2(e01, e23);
                } else if (tid < 768) {       // h -> xh[2560:3072)
                    int i = tid - 640;
                    *(uint2*)&xhb[b * KG_ + KX_ + i * 4] = *(const uint2*)&hb[b * HH_ + i * 4];
                } else if (tid < 768 + PP_) { // alphas
                    alphas[((size_t)b * TT_ + t) * PP_ + (tid - 768)] = s_sa[tid - 768];
                }
            }
        }
        gbar(bar);
        // ---- PH2: gates GEMM + LSTM pointwise (blocks 0..31) ----
        if (blk < 32) {
            const int q = wv & 3, kc = wv >> 2;
            const int jb = blk;
            const int nt = q * 32 + jb;
            f32x4 acc[2] = {};
            const unsigned short* a_base = xhb + (size_t)r * KG_ + g * 8;
#pragma unroll 4
            for (int i = 0; i < 24; i++) {
                int ks = kc * 24 + i;
                bf16x8 a0 = *(const bf16x8*)(a_base + ks * 32);
                bf16x8 a1 = *(const bf16x8*)(a_base + 16 * KG_ + ks * 32);
                bf16x8 bf = *(const bf16x8*)(wgf + ((size_t)(nt * 96 + ks) * 64 + lane) * 8);
                acc[0] = mfma16(a0, bf, acc[0]);
                acc[1] = mfma16(a1, bf, acc[1]);
            }
#pragma unroll
            for (int a = 0; a < 2; a++)
#pragma unroll
                for (int j = 0; j < 4; j++)
                    s_part[wv][16 * a + 4 * g + j][r] = acc[a][j];
            __syncthreads();
            {
                int qq = tid >> 8, s2 = tid & 255;
                int m = s2 >> 3, j0 = (s2 & 7) * 2;
#pragma unroll
                for (int jj = 0; jj < 2; jj++) {
                    int jc = j0 + jj;
                    s_gsum[qq][m][jc] = s_part[qq][m][jc] + s_part[4 + qq][m][jc]
                                      + s_part[8 + qq][m][jc] + s_part[12 + qq][m][jc];
                }
            }
            __syncthreads();
            if (tid < 512) {
                int m = tid >> 4, jc = tid & 15;
                int jg = jb * 16 + jc;
                float gi = s_gsum[0][m][jc] + bih[jg] + bhh[jg];
                float gf = s_gsum[1][m][jc] + bih[HH_ + jg] + bhh[HH_ + jg];
                float gg = s_gsum[2][m][jc] + bih[2 * HH_ + jg] + bhh[2 * HH_ + jg];
                float go = s_gsum[3][m][jc] + bih[3 * HH_ + jg] + bhh[3 * HH_ + jg];
                int ci = m * HH_ + jg;
                float cn = sigf(gf) * c[ci] + sigf(gi) * ftanh(gg);
                float hn = sigf(go) * ftanh(cn);
                c[ci] = cn;
                hb[ci] = bf16b(hn);
            }
        }
        gbar(bar);
        // ---- PH3: out GEMM + next-step hmats (all blocks) ----
        {
            int gwid = blk * 16 + wv;
            if (gwid < NTV_) {
                f32x4 acc[2] = {};
                const unsigned short* a_base = hb + (size_t)r * HH_ + g * 8;
#pragma unroll
                for (int ks = 0; ks < HH_ / 32; ks++) {
                    bf16x8 a0 = *(const bf16x8*)(a_base + ks * 32);
                    bf16x8 a1 = *(const bf16x8*)(a_base + 16 * HH_ + ks * 32);
                    bf16x8 bf = *(const bf16x8*)(wof + ((size_t)(gwid * 16 + ks) * 64 + lane) * 8);
                    acc[0] = mfma16(a0, bf, acc[0]);
                    acc[1] = mfma16(a1, bf, acc[1]);
                }
                int n = gwid * 16 + r;
                float bn = bout[n];
#pragma unroll
                for (int a = 0; a < 2; a++)
#pragma unroll
                    for (int j = 0; j < 4; j++) {
                        int m = 16 * a + 4 * g + j;
                        preds[((size_t)m * TT_ + t) * VV_ + n] = acc[a][j] + bn;
                    }
            } else if (gwid < NTV_ + NTH_) {
                hmats_body(gwid - NTV_, lane, hb, whf, bah, bfb, hWatt, gate);
            }
        }
        gbar(bar);
    }
}

// ---------------- launcher ----------------

extern "C" void kernel_launch(void* const* d_in, const int* in_sizes, int n_in,
                              void* d_out, int out_size, void* d_ws, size_t ws_size,
                              hipStream_t stream) {
    const float* img     = (const float*)d_in[0];
    const int*   caps    = (const int*)d_in[1];
    const float* Wih     = (const float*)d_in[2];
    const float* Whh     = (const float*)d_in[3];
    const float* bih     = (const float*)d_in[4];
    const float* bhh     = (const float*)d_in[5];
    const float* Winh    = (const float*)d_in[6];
    const float* binh    = (const float*)d_in[7];
    const float* Winc    = (const float*)d_in[8];
    const float* binc    = (const float*)d_in[9];
    const float* Wfb     = (const float*)d_in[10];
    const float* bfb     = (const float*)d_in[11];
    const float* Wout    = (const float*)d_in[12];
    const float* bout    = (const float*)d_in[13];
    const float* Wai     = (const float*)d_in[14];
    const float* bai     = (const float*)d_in[15];
    const float* Wah     = (const float*)d_in[16];
    const float* bah     = (const float*)d_in[17];
    const float* v_att   = (const float*)d_in[18];
    const float* b_v     = (const float*)d_in[19];
    const float* Emb     = (const float*)d_in[20];

    float* preds  = (float*)d_out;                               // [B,T,V]
    float* alphas = (float*)d_out + (size_t)BB_ * TT_ * VV_;     // [B,T,P]

    // ---- workspace layout (256B aligned) ----
    char* w = (char*)d_ws;
    size_t off = 0;
    auto alloc = [&](size_t bytes) {
        char* p = w + off;
        off += (bytes + 255) & ~(size_t)255;
        return p;
    };
    unsigned short* imgb = (unsigned short*)alloc((size_t)BB_ * PP_ * DD_ * 2); // 25.7MB
    unsigned short* wof  = (unsigned short*)alloc((size_t)HH_ * VV_ * 2);       // 30.7MB
    unsigned short* wgf  = (unsigned short*)alloc((size_t)KG_ * 2048 * 2);      // 12.6MB
    unsigned short* waf  = (unsigned short*)alloc((size_t)DD_ * HH_ * 2);       // 2.1MB
    unsigned short* whf  = (unsigned short*)alloc((size_t)HH_ * KX_ * 2);       // 2.6MB
    unsigned short* wif  = (unsigned short*)alloc((size_t)DD_ * 1024 * 2);      // 4.2MB
    unsigned short* attb = (unsigned short*)alloc((size_t)BB_ * PP_ * HH_ * 2); // 6.4MB
    unsigned short* avgb = (unsigned short*)alloc((size_t)BB_ * DD_ * 2);
    float* c       = (float*)alloc((size_t)BB_ * HH_ * 4);
    float* hWatt   = (float*)alloc((size_t)BB_ * HH_ * 4);
    float* gate    = (float*)alloc((size_t)BB_ * DD_ * 4);
    unsigned short* hb  = (unsigned short*)alloc((size_t)BB_ * HH_ * 2);
    unsigned short* xhb = (unsigned short*)alloc((size_t)BB_ * KG_ * 2);
    unsigned* bar = (unsigned*)alloc(256);
    (void)ws_size;

    hipMemsetAsync(bar, 0, 256, stream);

    // ---- one-time conversions / precompute ----
    k_cvt_all<<<19020, 256, 0, stream>>>(img, imgb, Wout, wof, Wai, waf,
                                         Wah, Wfb, whf, Wih, Whh, wgf,
                                         Winh, Winc, wif);
    k_meanpool<<<BB_, 256, 0, stream>>>(img, avgb);
    k_init_mfma<<<16, 256, 0, stream>>>(avgb, wif, binh, binc, c, hb);
    k_attimg_mfma<<<196, 256, 0, stream>>>(imgb, waf, bai, attb);

    // ---- the entire 19-step recurrence in one persistent kernel ----
    k_persist<<<NBLK_, 1024, 0, stream>>>(attb, imgb, wgf, wof, whf,
                                          bih, bhh, bout, bah, bfb,
                                          v_att, b_v, Emb, caps,
                                          c, hb, xhb, hWatt, gate,
                                          preds, alphas, bar);
}

// Round 6
// 2844.731 us; speedup vs baseline: 2.7919x; 2.7919x over previous
//
#include <hip/hip_runtime.h>
#include <hip/hip_bf16.h>

// ---- problem constants ----
#define BB_ 32      // batch
#define PP_ 196     // pixels
#define DD_ 2048    // encoder dim
#define HH_ 512     // hidden
#define VV_ 30000   // vocab
#define TT_ 19      // timesteps
#define KX_ 2560    // H + D
#define KG_ 3072    // H + D + H
#define PNB_ 128    // persistent grid (co-resident trivially)
#define NTV_ 1875   // out-GEMM n-tiles (30000/16)

typedef __attribute__((ext_vector_type(8))) short bf16x8;   // 8 bf16 (4 VGPRs)
typedef __attribute__((ext_vector_type(4))) float f32x4;

__device__ __forceinline__ unsigned short bf16b(float x) {
    __hip_bfloat16 h = __float2bfloat16(x);
    unsigned short u; __builtin_memcpy(&u, &h, 2); return u;
}
__device__ __forceinline__ float b2f(unsigned short u) {
    return __uint_as_float((unsigned int)u << 16);
}
__device__ __forceinline__ float sigf(float x) { return 1.f / (1.f + __expf(-x)); }
__device__ __forceinline__ float ftanh(float x) {
    return 1.f - 2.f / (__expf(2.f * x) + 1.f);
}
__device__ __forceinline__ f32x4 mfma16(bf16x8 a, bf16x8 b, f32x4 c) {
    return __builtin_amdgcn_mfma_f32_16x16x32_bf16(a, b, c, 0, 0, 0);
}

// ---- MALL-coherent (agent-scope, relaxed) access helpers: sc0/sc1 ops,
// serviced at Infinity Cache, NO L2 flush instructions ----
__device__ __forceinline__ void st_u32c(void* p, unsigned v) {
    __hip_atomic_store((unsigned*)p, v, __ATOMIC_RELAXED, __HIP_MEMORY_SCOPE_AGENT);
}
__device__ __forceinline__ unsigned ld_u32c(const void* p) {
    return __hip_atomic_load((const unsigned*)p, __ATOMIC_RELAXED, __HIP_MEMORY_SCOPE_AGENT);
}
__device__ __forceinline__ void st_u64c(void* p, unsigned long long v) {
    __hip_atomic_store((unsigned long long*)p, v, __ATOMIC_RELAXED, __HIP_MEMORY_SCOPE_AGENT);
}
__device__ __forceinline__ unsigned long long ld_u64c(const void* p) {
    return __hip_atomic_load((const unsigned long long*)p, __ATOMIC_RELAXED, __HIP_MEMORY_SCOPE_AGENT);
}
__device__ __forceinline__ bf16x8 ld_bf8c(const unsigned short* p) {
    union { unsigned long long q[2]; bf16x8 v; } u;
    u.q[0] = ld_u64c(p);
    u.q[1] = ld_u64c(p + 4);
    return u.v;
}
__device__ __forceinline__ float ld_f32c(const float* p) {
    return __uint_as_float(ld_u32c(p));
}

// grid barrier with NO L2 writeback/invalidate: relaxed agent atomics only.
// bar[0]=arrivals, bar[1]=generation. Requires all PNB_ blocks co-resident.
__device__ __forceinline__ void gbar(unsigned* bar) {
    asm volatile("s_waitcnt vmcnt(0)" ::: "memory");  // my sc-stores reached MALL
    __syncthreads();
    if (threadIdx.x == 0) {
        unsigned gen = __hip_atomic_load(&bar[1], __ATOMIC_RELAXED, __HIP_MEMORY_SCOPE_AGENT);
        unsigned arr = __hip_atomic_fetch_add(&bar[0], 1u, __ATOMIC_RELAXED, __HIP_MEMORY_SCOPE_AGENT);
        if (arr == PNB_ - 1u) {
            __hip_atomic_store(&bar[0], 0u, __ATOMIC_RELAXED, __HIP_MEMORY_SCOPE_AGENT);
            asm volatile("s_waitcnt vmcnt(0)" ::: "memory");  // order reset before gen bump
            __hip_atomic_store(&bar[1], gen + 1u, __ATOMIC_RELAXED, __HIP_MEMORY_SCOPE_AGENT);
        } else {
            while (__hip_atomic_load(&bar[1], __ATOMIC_RELAXED, __HIP_MEMORY_SCOPE_AGENT) == gen)
                __builtin_amdgcn_s_sleep(2);
        }
    }
    asm volatile("" ::: "memory");
    __syncthreads();
}

// ---------------- fused conversion kernel ----------------

__device__ __forceinline__ void d_cvt8(int bid, int tid,
        const float* __restrict__ src, unsigned short* __restrict__ dst) {
    size_t i0 = ((size_t)bid * 256 + tid) * 8;
    float4 a = *(const float4*)&src[i0];
    float4 b = *(const float4*)&src[i0 + 4];
    bf16x8 v;
    v[0]=bf16b(a.x); v[1]=bf16b(a.y); v[2]=bf16b(a.z); v[3]=bf16b(a.w);
    v[4]=bf16b(b.x); v[5]=bf16b(b.y); v[6]=bf16b(b.z); v[7]=bf16b(b.w);
    *(bf16x8*)&dst[i0] = v;
}

__device__ __forceinline__ void d_nsplit(int bid, int tid,
        const float* __restrict__ A, int NA, const float* __restrict__ Bp, int NB,
        int K, unsigned short* __restrict__ dst) {
    int gid = bid * 256 + tid;
    int lane = gid & 63, rest = gid >> 6;
    int KS = K >> 5;
    int ks = rest % KS, nt = rest / KS;
    int g = lane >> 4, r = lane & 15;
    int k0 = ks * 32 + g * 8;
    int n = nt * 16 + r;
    const float* src; int stride, col;
    if (n < NA) { src = A; stride = NA; col = n; }
    else        { src = Bp; stride = NB; col = n - NA; }
    bf16x8 v;
#pragma unroll
    for (int i = 0; i < 8; i++)
        v[i] = bf16b(src[(size_t)(k0 + i) * stride + col]);
    *(bf16x8*)&dst[(size_t)gid * 8] = v;
}

__device__ __forceinline__ void d_ksplit(int bid, int tid,
        const float* __restrict__ A, int KA, const float* __restrict__ Bp,
        int K, int N, unsigned short* __restrict__ dst) {
    int gid = bid * 256 + tid;
    int lane = gid & 63, rest = gid >> 6;
    int KS = K >> 5;
    int ks = rest % KS, nt = rest / KS;
    int g = lane >> 4, r = lane & 15;
    int k0 = ks * 32 + g * 8;
    int n = nt * 16 + r;
    bf16x8 v;
#pragma unroll
    for (int i = 0; i < 8; i++) {
        int k = k0 + i;
        const float* src = (k < KA) ? &A[(size_t)k * N] : &Bp[(size_t)(k - KA) * N];
        v[i] = bf16b(src[n]);
    }
    *(bf16x8*)&dst[(size_t)gid * 8] = v;
}

// blocks: img 6272 | wout 7500 | wai 512 | whf 640 | wgf 3072 | wif 1024
__global__ __launch_bounds__(256) void k_cvt_all(
        const float* __restrict__ img, unsigned short* __restrict__ imgb,
        const float* __restrict__ Wout, unsigned short* __restrict__ wof,
        const float* __restrict__ Wai, unsigned short* __restrict__ waf,
        const float* __restrict__ Wah, const float* __restrict__ Wfb,
        unsigned short* __restrict__ whf,
        const float* __restrict__ Wih, const float* __restrict__ Whh,
        unsigned short* __restrict__ wgf,
        const float* __restrict__ Winh, const float* __restrict__ Winc,
        unsigned short* __restrict__ wif) {
    int b = blockIdx.x, t = threadIdx.x;
    if (b < 6272)       d_cvt8(b, t, img, imgb);
    else if (b < 13772) d_nsplit(b - 6272, t, Wout, VV_, Wout, 0, HH_, wof);
    else if (b < 14284) d_nsplit(b - 13772, t, Wai, HH_, Wai, 0, DD_, waf);
    else if (b < 14924) d_nsplit(b - 14284, t, Wah, HH_, Wfb, DD_, HH_, whf);
    else if (b < 17996) d_ksplit(b - 14924, t, Wih, KX_, Whh, KG_, 2048, wgf);
    else                d_nsplit(b - 17996, t, Winh, HH_, Winc, HH_, DD_, wif);
}

// ---------------- precompute ----------------

__global__ __launch_bounds__(256) void k_meanpool(const float* __restrict__ img,
                                                  unsigned short* __restrict__ avgb) {
    int b = blockIdx.x, tid = threadIdx.x;
    int d0 = tid * 8;
    const float* p = img + (size_t)b * PP_ * DD_ + d0;
    float s[8] = {};
    for (int i = 0; i < PP_; i++) {
        float4 a = *(const float4*)&p[(size_t)i * DD_];
        float4 c = *(const float4*)&p[(size_t)i * DD_ + 4];
        s[0]+=a.x; s[1]+=a.y; s[2]+=a.z; s[3]+=a.w;
        s[4]+=c.x; s[5]+=c.y; s[6]+=c.z; s[7]+=c.w;
    }
    bf16x8 v;
#pragma unroll
    for (int i = 0; i < 8; i++) v[i] = bf16b(s[i] * (1.0f / PP_));
    *(bf16x8*)&avgb[b * DD_ + d0] = v;
}

__global__ __launch_bounds__(256) void k_init_mfma(const unsigned short* __restrict__ avgb,
        const unsigned short* __restrict__ wif, const float* __restrict__ binh,
        const float* __restrict__ binc, float* __restrict__ c,
        unsigned short* __restrict__ hb) {
    int wid = blockIdx.x * 4 + (threadIdx.x >> 6);
    int lane = threadIdx.x & 63;
    int g = lane >> 4, r = lane & 15;
    f32x4 acc[2] = {};
    const unsigned short* a_base = avgb + (size_t)r * DD_ + g * 8;
#pragma unroll 4
    for (int ks = 0; ks < DD_ / 32; ks++) {
        bf16x8 a0 = *(const bf16x8*)(a_base + ks * 32);
        bf16x8 a1 = *(const bf16x8*)(a_base + 16 * DD_ + ks * 32);
        bf16x8 bf = *(const bf16x8*)(wif + ((size_t)(wid * 64 + ks) * 64 + lane) * 8);
        acc[0] = mfma16(a0, bf, acc[0]);
        acc[1] = mfma16(a1, bf, acc[1]);
    }
    int n = wid * 16 + r;
#pragma unroll
    for (int a = 0; a < 2; a++)
#pragma unroll
        for (int j = 0; j < 4; j++) {
            int m = 16 * a + 4 * g + j;
            float v = ftanh(acc[a][j] + ((n < HH_) ? binh[n] : binc[n - HH_]));
            if (n < HH_) hb[m * HH_ + n] = bf16b(v);
            else c[m * HH_ + (n - HH_)] = v;
        }
}

// att_img(bf16) = img @ W_att_img + b; wave tile 64x64
__global__ __launch_bounds__(256) void k_attimg_mfma(const unsigned short* __restrict__ imgb,
        const unsigned short* __restrict__ waf, const float* __restrict__ bias,
        unsigned short* __restrict__ attb) {
    int wid = blockIdx.x * 4 + (threadIdx.x >> 6);
    int lane = threadIdx.x & 63;
    int g = lane >> 4, r = lane & 15;
    int mt = wid >> 3, ntb = wid & 7;
    int m0 = mt * 64, nt0 = ntb * 4;
    f32x4 acc[4][4] = {};
    const unsigned short* a_base = imgb + (size_t)(m0 + r) * DD_ + g * 8;
    for (int ks = 0; ks < DD_ / 32; ks++) {
        bf16x8 a[4], b[4];
#pragma unroll
        for (int mi = 0; mi < 4; mi++)
            a[mi] = *(const bf16x8*)(a_base + (size_t)(16 * mi) * DD_ + ks * 32);
#pragma unroll
        for (int ni = 0; ni < 4; ni++)
            b[ni] = *(const bf16x8*)(waf + (((size_t)(nt0 + ni) * 64 + ks) * 64 + lane) * 8);
#pragma unroll
        for (int mi = 0; mi < 4; mi++)
#pragma unroll
            for (int ni = 0; ni < 4; ni++)
                acc[mi][ni] = mfma16(a[mi], b[ni], acc[mi][ni]);
    }
#pragma unroll
    for (int mi = 0; mi < 4; mi++)
#pragma unroll
        for (int ni = 0; ni < 4; ni++) {
            int n = (nt0 + ni) * 16 + r;
            float bn = bias[n];
#pragma unroll
            for (int j = 0; j < 4; j++) {
                int m = m0 + 16 * mi + 4 * g + j;
                attb[(size_t)m * HH_ + n] = bf16b(acc[mi][ni][j] + bn);
            }
        }
}

// ---------------- persistent recurrence kernel ----------------
// 128 blocks x 1024 threads. Per step: PH_H (hmats) | bar | PH_B (att+ctx+x)
// | bar | PH_C (gates+lstm) | bar.  Cross-block data via MALL-coherent ops.

__global__ __launch_bounds__(1024) void k_persist(
        const unsigned short* __restrict__ attb, const unsigned short* __restrict__ imgb,
        const unsigned short* __restrict__ wgf, const unsigned short* __restrict__ whf,
        const float* __restrict__ bih, const float* __restrict__ bhh,
        const float* __restrict__ bah, const float* __restrict__ bfb,
        const float* __restrict__ v_att, const float* __restrict__ b_v,
        const float* __restrict__ Emb, const int* __restrict__ caps,
        float* __restrict__ c, unsigned short* __restrict__ hb,
        unsigned short* __restrict__ xhb, float* __restrict__ hWatt,
        float* __restrict__ gate, unsigned short* __restrict__ hall,
        float* __restrict__ alphas, unsigned* __restrict__ bar) {
    __shared__ float s_part[4][8][BB_][16];   // 64 KB (PH_C partials)
    __shared__ float s_gsum[4][BB_][16];      //  8 KB
    __shared__ unsigned short s_h[BB_][16];   // PH_C h-slice pack
    __shared__ float s_e[PP_];
    __shared__ float s_sa[PP_];
    __shared__ float s_red[256];
    __shared__ float s_gate[512];
    __shared__ float s_ctx2[2][512];
    __shared__ unsigned short s_xu[512];
    const int tid = threadIdx.x;
    const int wv = tid >> 6, lane = tid & 63;
    const int g = lane >> 4, r = lane & 15;
    const int blk = blockIdx.x;

    for (int t = 0; t < TT_; t++) {
        // ================= PH_H: [hWatt|gate] = h @ [Wah|Wfb] =================
        if (blk < 40 && wv < 4) {
            int wid = blk * 4 + wv;              // 0..159 n-tiles
            f32x4 acc[2] = {};
            const unsigned short* a_base = hb + (size_t)r * HH_ + g * 8;
#pragma unroll
            for (int ks = 0; ks < HH_ / 32; ks++) {
                bf16x8 a0 = ld_bf8c(a_base + ks * 32);
                bf16x8 a1 = ld_bf8c(a_base + 16 * HH_ + ks * 32);
                bf16x8 bf = *(const bf16x8*)(whf + ((size_t)(wid * 16 + ks) * 64 + lane) * 8);
                acc[0] = mfma16(a0, bf, acc[0]);
                acc[1] = mfma16(a1, bf, acc[1]);
            }
            int n = wid * 16 + r;
#pragma unroll
            for (int a = 0; a < 2; a++)
#pragma unroll
                for (int j = 0; j < 4; j++) {
                    int m = 16 * a + 4 * g + j;
                    float v = acc[a][j];
                    if (n < HH_)
                        st_u32c(&hWatt[m * HH_ + n], __float_as_uint(v + bah[n]));
                    else
                        st_u32c(&gate[m * DD_ + (n - HH_)],
                                __float_as_uint(sigf(v + bfb[n - HH_])));
                }
        }
        gbar(bar);
        // ================= PH_B: energy+softmax+ctx+x (4 blocks per b) ========
        {
            const int b = blk >> 2, q = blk & 3;
            // hWatt/v_att per-lane slices (8 f32 each)
            float hw8[8], vv8[8];
            {
                const float* hwp = hWatt + (size_t)b * HH_ + lane * 8;
#pragma unroll
                for (int i = 0; i < 4; i++) {
                    unsigned long long u = ld_u64c(hwp + i * 2);
                    hw8[2*i]   = __uint_as_float((unsigned)u);
                    hw8[2*i+1] = __uint_as_float((unsigned)(u >> 32));
                }
                float4 v0 = *(const float4*)&v_att[lane * 8];
                float4 v1 = *(const float4*)&v_att[lane * 8 + 4];
                vv8[0]=v0.x; vv8[1]=v0.y; vv8[2]=v0.z; vv8[3]=v0.w;
                vv8[4]=v1.x; vv8[5]=v1.y; vv8[6]=v1.z; vv8[7]=v1.w;
            }
            // gate quarter -> LDS
            if (tid < 256) {
                unsigned long long u = ld_u64c(gate + (size_t)b * DD_ + q * 512 + tid * 2);
                s_gate[tid * 2]     = __uint_as_float((unsigned)u);
                s_gate[tid * 2 + 1] = __uint_as_float((unsigned)(u >> 32));
            }
            // energy (replicated per block): all 196 rows
            float bv0 = b_v[0];
            const unsigned short* ab = attb + (size_t)b * PP_ * HH_ + lane * 8;
            for (int p = wv; p < PP_; p += 16) {
                bf16x8 av = *(const bf16x8*)(ab + (size_t)p * HH_);
                float acc = 0.f;
#pragma unroll
                for (int j = 0; j < 8; j++)
                    acc += vv8[j] * ftanh(b2f((unsigned short)av[j]) + hw8[j]);
#pragma unroll
                for (int off = 32; off > 0; off >>= 1) acc += __shfl_down(acc, off);
                if (lane == 0) s_e[p] = acc + bv0;
            }
            __syncthreads();
            // softmax over 196 (first 256 threads tree-reduce)
            float ev = -1e30f;
            if (tid < PP_) ev = s_e[tid];
            if (tid < 256) s_red[tid] = ev;
            __syncthreads();
            for (int s = 128; s > 0; s >>= 1) {
                if (tid < s) s_red[tid] = fmaxf(s_red[tid], s_red[tid + s]);
                __syncthreads();
            }
            float mx = s_red[0];
            __syncthreads();
            float pv = (tid < PP_) ? __expf(ev - mx) : 0.f;
            if (tid < 256) s_red[tid] = pv;
            __syncthreads();
            for (int s = 128; s > 0; s >>= 1) {
                if (tid < s) s_red[tid] += s_red[tid + s];
                __syncthreads();
            }
            float inv = 1.f / s_red[0];
            if (tid < PP_) s_sa[tid] = pv * inv;
            __syncthreads();
            // context for this 512-wide quarter: 2 threads per col (p-split)
            {
                int col = tid & 511, half = tid >> 9;
                const unsigned short* ib = imgb + (size_t)b * PP_ * DD_ + q * 512 + col
                                         + (size_t)half * 98 * DD_;
                float acc = 0.f;
#pragma unroll 4
                for (int p = 0; p < 98; p++)
                    acc += s_sa[half * 98 + p] * b2f(ib[(size_t)p * DD_]);
                s_ctx2[half][col] = acc;
            }
            __syncthreads();
            if (tid < 512) {
                float xv = (s_ctx2[0][tid] + s_ctx2[1][tid]) * s_gate[tid];
                s_xu[tid] = bf16b(xv);
            }
            __syncthreads();
            if (tid < 128) {   // pack 4 bf16 -> u64 coherent store
                unsigned long long u =
                      (unsigned long long)s_xu[tid*4]
                    | ((unsigned long long)s_xu[tid*4+1] << 16)
                    | ((unsigned long long)s_xu[tid*4+2] << 32)
                    | ((unsigned long long)s_xu[tid*4+3] << 48);
                st_u64c(xhb + (size_t)b * KG_ + HH_ + q * 512 + tid * 4, u);
            }
            if (q == 0) {
                if (tid >= 256 && tid < 384) {       // emb -> x[0:512)
                    int i = tid - 256;
                    int tok = caps[b * 20 + t];
                    float4 evec = *(const float4*)&Emb[(size_t)tok * HH_ + i * 4];
                    unsigned long long u =
                          (unsigned long long)bf16b(evec.x)
                        | ((unsigned long long)bf16b(evec.y) << 16)
                        | ((unsigned long long)bf16b(evec.z) << 32)
                        | ((unsigned long long)bf16b(evec.w) << 48);
                    st_u64c(xhb + (size_t)b * KG_ + i * 4, u);
                } else if (tid >= 384 && tid < 512) { // h -> x[2560:3072)
                    int i = tid - 384;
                    unsigned long long u = ld_u64c(hb + (size_t)b * HH_ + i * 4);
                    st_u64c(xhb + (size_t)b * KG_ + KX_ + i * 4, u);
                } else if (tid >= 512 && tid < 512 + PP_) {
                    alphas[((size_t)b * TT_ + t) * PP_ + (tid - 512)] = s_sa[tid - 512];
                }
            }
        }
        gbar(bar);
        // ================= PH_C: gates GEMM + LSTM (blocks 0..31) =============
        if (blk < 32) {
            const int jb = blk;
            const int kc = wv >> 1, qh = wv & 1;   // 8 k-chunks x 2 q-halves
            f32x4 acc[2][2] = {};                  // [qi][mi]
            const unsigned short* a_base = xhb + (size_t)r * KG_ + g * 8;
#pragma unroll 2
            for (int i = 0; i < 12; i++) {
                int ks = kc * 12 + i;
                bf16x8 a0 = ld_bf8c(a_base + ks * 32);
                bf16x8 a1 = ld_bf8c(a_base + 16 * KG_ + ks * 32);
#pragma unroll
                for (int qi = 0; qi < 2; qi++) {
                    int nt = (qh * 2 + qi) * 32 + jb;
                    bf16x8 bf = *(const bf16x8*)(wgf + ((size_t)(nt * 96 + ks) * 64 + lane) * 8);
                    acc[qi][0] = mfma16(a0, bf, acc[qi][0]);
                    acc[qi][1] = mfma16(a1, bf, acc[qi][1]);
                }
            }
#pragma unroll
            for (int qi = 0; qi < 2; qi++)
#pragma unroll
                for (int a = 0; a < 2; a++)
#pragma unroll
                    for (int j = 0; j < 4; j++)
                        s_part[qh * 2 + qi][kc][16 * a + 4 * g + j][r] = acc[qi][a][j];
            __syncthreads();
#pragma unroll
            for (int it = 0; it < 2; it++) {
                int idx = tid + it * 1024;         // 2048 outputs
                int qq = idx >> 9, m = (idx >> 4) & 31, jc = idx & 15;
                float s = 0.f;
#pragma unroll
                for (int kk = 0; kk < 8; kk++) s += s_part[qq][kk][m][jc];
                s_gsum[qq][m][jc] = s;
            }
            __syncthreads();
            if (tid < 512) {
                int m = tid >> 4, jc = tid & 15;
                int jg = jb * 16 + jc;
                float gi = s_gsum[0][m][jc] + bih[jg] + bhh[jg];
                float gf = s_gsum[1][m][jc] + bih[HH_ + jg] + bhh[HH_ + jg];
                float gg = s_gsum[2][m][jc] + bih[2 * HH_ + jg] + bhh[2 * HH_ + jg];
                float go = s_gsum[3][m][jc] + bih[3 * HH_ + jg] + bhh[3 * HH_ + jg];
                int ci = m * HH_ + jg;
                float cn = sigf(gf) * c[ci] + sigf(gi) * ftanh(gg);   // c block-private
                float hn = sigf(go) * ftanh(cn);
                c[ci] = cn;
                unsigned short hv = bf16b(hn);
                s_h[m][jc] = hv;
                hall[((size_t)t * BB_ + m) * HH_ + jg] = hv;          // normal store
            }
            __syncthreads();
            if (tid < 256) {   // pack h pairs -> coherent u32 stores
                int m = tid >> 3, j2 = (tid & 7) * 2;
                unsigned u = (unsigned)s_h[m][j2] | ((unsigned)s_h[m][j2 + 1] << 16);
                st_u32c(hb + (size_t)m * HH_ + jb * 16 + j2, u);
            }
        }
        gbar(bar);
    }
}

// ---------------- batched output GEMM: preds = hall @ W_out + b ----------------
// grid (469, 3): wave nt-tile, y = t-chunk of 8
__global__ __launch_bounds__(256) void k_outgemm(const unsigned short* __restrict__ hall,
        const unsigned short* __restrict__ wof, const float* __restrict__ bout,
        float* __restrict__ preds) {
    int nt = blockIdx.x * 4 + (threadIdx.x >> 6);
    if (nt >= NTV_) return;
    int lane = threadIdx.x & 63;
    int g = lane >> 4, r = lane & 15;
    int t0 = blockIdx.y * 8;
    int tlen = (t0 + 8 <= TT_) ? 8 : (TT_ - t0);
    f32x4 acc[8][2] = {};
#pragma unroll
    for (int ks = 0; ks < HH_ / 32; ks++) {
        bf16x8 bf = *(const bf16x8*)(wof + ((size_t)(nt * 16 + ks) * 64 + lane) * 8);
        for (int ti = 0; ti < tlen; ti++) {
            const unsigned short* a_base = hall + ((size_t)(t0 + ti) * BB_ + r) * HH_ + g * 8;
            bf16x8 a0 = *(const bf16x8*)(a_base + ks * 32);
            bf16x8 a1 = *(const bf16x8*)(a_base + 16 * HH_ + ks * 32);
            acc[ti][0] = mfma16(a0, bf, acc[ti][0]);
            acc[ti][1] = mfma16(a1, bf, acc[ti][1]);
        }
    }
    int n = nt * 16 + r;
    float bn = bout[n];
    for (int ti = 0; ti < tlen; ti++) {
        int t = t0 + ti;
#pragma unroll
        for (int a = 0; a < 2; a++)
#pragma unroll
            for (int j = 0; j < 4; j++) {
                int m = 16 * a + 4 * g + j;    // batch index
                preds[((size_t)m * TT_ + t) * VV_ + n] = acc[ti][a][j] + bn;
            }
    }
}

// ---------------- launcher ----------------

extern "C" void kernel_launch(void* const* d_in, const int* in_sizes, int n_in,
                              void* d_out, int out_size, void* d_ws, size_t ws_size,
                              hipStream_t stream) {
    const float* img     = (const float*)d_in[0];
    const int*   caps    = (const int*)d_in[1];
    const float* Wih     = (const float*)d_in[2];
    const float* Whh     = (const float*)d_in[3];
    const float* bih     = (const float*)d_in[4];
    const float* bhh     = (const float*)d_in[5];
    const float* Winh    = (const float*)d_in[6];
    const float* binh    = (const float*)d_in[7];
    const float* Winc    = (const float*)d_in[8];
    const float* binc    = (const float*)d_in[9];
    const float* Wfb     = (const float*)d_in[10];
    const float* bfb     = (const float*)d_in[11];
    const float* Wout    = (const float*)d_in[12];
    const float* bout    = (const float*)d_in[13];
    const float* Wai     = (const float*)d_in[14];
    const float* bai     = (const float*)d_in[15];
    const float* Wah     = (const float*)d_in[16];
    const float* bah     = (const float*)d_in[17];
    const float* v_att   = (const float*)d_in[18];
    const float* b_v     = (const float*)d_in[19];
    const float* Emb     = (const float*)d_in[20];

    float* preds  = (float*)d_out;                               // [B,T,V]
    float* alphas = (float*)d_out + (size_t)BB_ * TT_ * VV_;     // [B,T,P]

    char* w = (char*)d_ws;
    size_t off = 0;
    auto alloc = [&](size_t bytes) {
        char* p = w + off;
        off += (bytes + 255) & ~(size_t)255;
        return p;
    };
    unsigned short* imgb = (unsigned short*)alloc((size_t)BB_ * PP_ * DD_ * 2); // 25.7MB
    unsigned short* wof  = (unsigned short*)alloc((size_t)HH_ * VV_ * 2);       // 30.7MB
    unsigned short* wgf  = (unsigned short*)alloc((size_t)KG_ * 2048 * 2);      // 12.6MB
    unsigned short* waf  = (unsigned short*)alloc((size_t)DD_ * HH_ * 2);       // 2.1MB
    unsigned short* whf  = (unsigned short*)alloc((size_t)HH_ * KX_ * 2);       // 2.6MB
    unsigned short* wif  = (unsigned short*)alloc((size_t)DD_ * 1024 * 2);      // 4.2MB
    unsigned short* attb = (unsigned short*)alloc((size_t)BB_ * PP_ * HH_ * 2); // 6.4MB
    unsigned short* avgb = (unsigned short*)alloc((size_t)BB_ * DD_ * 2);
    unsigned short* hall = (unsigned short*)alloc((size_t)TT_ * BB_ * HH_ * 2); // 622KB
    float* c       = (float*)alloc((size_t)BB_ * HH_ * 4);
    float* hWatt   = (float*)alloc((size_t)BB_ * HH_ * 4);
    float* gate    = (float*)alloc((size_t)BB_ * DD_ * 4);
    unsigned short* hb  = (unsigned short*)alloc((size_t)BB_ * HH_ * 2);
    unsigned short* xhb = (unsigned short*)alloc((size_t)BB_ * KG_ * 2);
    unsigned* bar = (unsigned*)alloc(256);
    (void)ws_size;

    hipMemsetAsync(bar, 0, 256, stream);
    k_cvt_all<<<19020, 256, 0, stream>>>(img, imgb, Wout, wof, Wai, waf,
                                         Wah, Wfb, whf, Wih, Whh, wgf,
                                         Winh, Winc, wif);
    k_meanpool<<<BB_, 256, 0, stream>>>(img, avgb);
    k_init_mfma<<<16, 256, 0, stream>>>(avgb, wif, binh, binc, c, hb);
    k_attimg_mfma<<<196, 256, 0, stream>>>(imgb, waf, bai, attb);

    k_persist<<<PNB_, 1024, 0, stream>>>(attb, imgb, wgf, whf,
                                         bih, bhh, bah, bfb, v_att, b_v,
                                         Emb, caps, c, hb, xhb, hWatt, gate,
                                         hall, alphas, bar);

    k_outgemm<<<dim3(469, 3), 256, 0, stream>>>(hall, wof, bout, preds);
}